// Round 3
// baseline (1891.341 us; speedup 1.0000x reference)
//
#include <hip/hip_runtime.h>

#define NN   20000
#define NE   320000
#define EAD  8
#define DIN  16
#define DOUT 16
#define HH   256      // DIN*DOUT
#define SLOPE 0.01f
#define EPB  64       // edges per block
#define BK   32       // w2 K-chunk staged in LDS (32 rows = 32 KB)

__device__ __forceinline__ float leakyf(float v) { return v >= 0.f ? v : SLOPE * v; }

// One fused NNConv message pass: per edge e
//   h = leaky(ea[e] @ w1 + b1)            [256]
//   W = h @ w2 + b2  (reshaped [16][16])
//   msg = x[src[e]] @ W                   [16]
//   atomicAdd(agg[dst[e]], msg); (opt) cnt[dst[e]]++
template<int COUNT>
__global__ __launch_bounds__(256, 1)
void edge_kernel(const float* __restrict__ x,     // [NN,16]
                 const int*   __restrict__ esrc,  // [NE]
                 const int*   __restrict__ edst,  // [NE]
                 const float* __restrict__ ea,    // [NE,8]
                 const float* __restrict__ w1,    // [8,256]
                 const float* __restrict__ b1,    // [256]
                 const float* __restrict__ w2,    // [256,256]
                 const float* __restrict__ b2,    // [256]
                 float* __restrict__ agg,         // [NN,16]
                 float* __restrict__ cnt)         // [NN]
{
    __shared__ float eaT[EAD][EPB];    // 2 KB, transposed: bank-friendly
    __shared__ float xs[EPB][DIN];     // 4 KB gathered source features
    __shared__ float hT[HH][EPB];      // 64 KB, h transposed [j][t]
    __shared__ float w2s[BK][HH];      // 32 KB w2 chunk
    __shared__ float msg_s[EPB][DOUT]; // 4 KB
    __shared__ int   ssrc[EPB];
    __shared__ int   sdst[EPB];
    // total LDS ~106.5 KB  (<=128 KB proven-safe static budget on gfx950)

    const int tid = threadIdx.x;
    const int e0  = blockIdx.x * EPB;

    if (tid < EPB) {
        ssrc[tid] = esrc[e0 + tid];
        sdst[tid] = edst[e0 + tid];
    }
    // load edge_attr transposed: 512 floats
    #pragma unroll
    for (int it = 0; it < 2; ++it) {
        int idx = it * 256 + tid;          // = k*64 + t
        int k = idx >> 6, t = idx & 63;
        eaT[k][t] = ea[(size_t)(e0 + t) * EAD + k];
    }
    // zero msg accumulator
    #pragma unroll
    for (int it = 0; it < 4; ++it)
        ((float*)msg_s)[it * 256 + tid] = 0.f;

    __syncthreads();

    // gather x[src] : 64 edges x 16 floats = 256 float4
    {
        int t = tid >> 2, p = tid & 3;
        float4 v = *(const float4*)(x + (size_t)ssrc[t] * DIN + p * 4);
        *(float4*)&xs[t][p * 4] = v;
    }

    // h phase: thread j computes h[j][t] for all 64 edges (staggered t: 2-way banks)
    {
        const int j = tid;
        float w1v[EAD];
        #pragma unroll
        for (int k = 0; k < EAD; ++k) w1v[k] = w1[k * HH + j];
        const float b = b1[j];
        for (int tt = 0; tt < EPB; ++tt) {
            int t = (tt + j) & 63;
            float a = b;
            #pragma unroll
            for (int k = 0; k < EAD; ++k) a += w1v[k] * eaT[k][t];
            hT[j][t] = leakyf(a);
        }
    }

    // GEMM: Wcore[t][c] = sum_j hT[j][t] * w2[j][c]
    // thread (rg=tid>>4, cg=tid&15): rows 4rg..4rg+3, cols {4cg + 64q + w}
    const int rg = tid >> 4;
    const int cg = tid & 15;
    float acc[4][16];
    #pragma unroll
    for (int r = 0; r < 4; ++r)
        #pragma unroll
        for (int c = 0; c < 16; ++c) acc[r][c] = 0.f;

    for (int kc = 0; kc < HH / BK; ++kc) {
        __syncthreads();   // protect w2s reuse; first iter: hT complete
        {
            const float4* gsrc = (const float4*)(w2 + (size_t)kc * BK * HH);
            float4* sv = (float4*)w2s;
            #pragma unroll
            for (int it = 0; it < BK * HH / 4 / 256; ++it)   // 8 float4 per thread
                sv[it * 256 + tid] = gsrc[it * 256 + tid];
        }
        __syncthreads();
        for (int jj = 0; jj < BK; ++jj) {
            const int j = kc * BK + jj;
            float hv[4];
            *(float4*)hv = *(const float4*)&hT[j][rg * 4];
            #pragma unroll
            for (int q = 0; q < 4; ++q) {
                float wv[4];
                *(float4*)wv = *(const float4*)&w2s[jj][cg * 4 + q * 64];
                #pragma unroll
                for (int r = 0; r < 4; ++r)
                    #pragma unroll
                    for (int w = 0; w < 4; ++w)
                        acc[r][q * 4 + w] += hv[r] * wv[w];
            }
        }
    }

    // epilogue: msg[t][o] = sum_i xs[t][i] * Wcore[t][16i+o]  (+ b2 term later)
    // thread's col c = 4cg+64q+w -> i = 4q + (cg>>2), o = 4(cg&3)+w
    {
        const int ib = cg >> 2;
        const int ob = (cg & 3) * 4;
        #pragma unroll
        for (int r = 0; r < 4; ++r) {
            const int t = rg * 4 + r;
            #pragma unroll
            for (int w = 0; w < 4; ++w) {
                float p = 0.f;
                #pragma unroll
                for (int q = 0; q < 4; ++q)
                    p += xs[t][q * 4 + ib] * acc[r][q * 4 + w];
                atomicAdd(&msg_s[t][ob + w], p);
            }
        }
    }
    __syncthreads();
    // scatter: 4 threads per edge, each 4 outputs; add b2 contribution
    {
        const int t = tid >> 2, og = tid & 3;
        const int d = sdst[t];
        #pragma unroll
        for (int oo = 0; oo < 4; ++oo) {
            const int o = og * 4 + oo;
            float m = msg_s[t][o];
            #pragma unroll
            for (int i = 0; i < DIN; ++i)
                m += xs[t][i] * b2[i * DOUT + o];
            atomicAdd(&agg[(size_t)d * DOUT + o], m);
        }
        if (COUNT && og == 0) atomicAdd(&cnt[d], 1.0f);
    }
}

// out[n][o] = agg[n][o]/max(cnt,1) + x[n]@root[:,o] + bias[o]  (opt leaky)
__global__ void finalize_kernel(const float* __restrict__ agg,
                                const float* __restrict__ cnt,
                                const float* __restrict__ xin,
                                const float* __restrict__ root, // [16,16]
                                const float* __restrict__ bias, // [16]
                                float* __restrict__ out,
                                int do_leaky)
{
    int idx = blockIdx.x * blockDim.x + threadIdx.x;
    if (idx >= NN * DOUT) return;
    int n = idx >> 4, o = idx & 15;
    float c = cnt[n];
    c = c > 1.f ? c : 1.f;
    float v = agg[idx] / c;
    #pragma unroll
    for (int i = 0; i < DIN; ++i)
        v += xin[n * DIN + i] * root[i * DOUT + o];
    v += bias[o];
    out[idx] = do_leaky ? leakyf(v) : v;
}

extern "C" void kernel_launch(void* const* d_in, const int* in_sizes, int n_in,
                              void* d_out, int out_size, void* d_ws, size_t ws_size,
                              hipStream_t stream)
{
    const float* x      = (const float*)d_in[0];
    const int*   ei     = (const int*)  d_in[1];
    const float* ea     = (const float*)d_in[2];
    const float* w1_0   = (const float*)d_in[3];
    const float* b1_0   = (const float*)d_in[4];
    const float* w2_0   = (const float*)d_in[5];
    const float* b2_0   = (const float*)d_in[6];
    const float* root_0 = (const float*)d_in[7];
    const float* bias_0 = (const float*)d_in[8];
    const float* w1_1   = (const float*)d_in[9];
    const float* b1_1   = (const float*)d_in[10];
    const float* w2_1   = (const float*)d_in[11];
    const float* b2_1   = (const float*)d_in[12];
    const float* root_1 = (const float*)d_in[13];
    const float* bias_1 = (const float*)d_in[14];

    const int* esrc = ei;
    const int* edst = ei + NE;

    // ws layout: agg [NN*16] | cnt [NN] | x1 [NN*16]   (agg reused across layers)
    float* agg = (float*)d_ws;
    float* cnt = agg + (size_t)NN * DOUT;
    float* x1  = cnt + NN;
    const size_t ws_need = ((size_t)2 * NN * DOUT + NN) * sizeof(float);
    if (ws_size < ws_need) return;  // fail loud-but-clean (absmax, not a GPU fault)

    // zero agg + cnt (contiguous)
    hipMemsetAsync(agg, 0, ((size_t)NN * DOUT + NN) * sizeof(float), stream);

    edge_kernel<1><<<NE / EPB, 256, 0, stream>>>(x, esrc, edst, ea,
                                                 w1_0, b1_0, w2_0, b2_0, agg, cnt);
    finalize_kernel<<<(NN * DOUT + 255) / 256, 256, 0, stream>>>(agg, cnt, x,
                                                 root_0, bias_0, x1, 1);
    // re-zero agg only (keep cnt: depends only on dst, reused by layer 1)
    hipMemsetAsync(agg, 0, (size_t)NN * DOUT * sizeof(float), stream);

    edge_kernel<0><<<NE / EPB, 256, 0, stream>>>(x1, esrc, edst, ea,
                                                 w1_1, b1_1, w2_1, b2_1, agg, cnt);
    finalize_kernel<<<(NN * DOUT + 255) / 256, 256, 0, stream>>>(agg, cnt, x1,
                                                 root_1, bias_1, (float*)d_out, 0);
}

// Round 4
// 483.507 us; speedup vs baseline: 3.9117x; 3.9117x over previous
//
#include <hip/hip_runtime.h>

#define NN   20000
#define NE   320000
#define EAD  8
#define DIN  16
#define DOUT 16
#define HH   256      // DIN*DOUT
#define SLOPE 0.01f
#define EPB  64       // edges per block

typedef __attribute__((ext_vector_type(8))) short bf16x8;   // 8 bf16 = 4 VGPRs
typedef __attribute__((ext_vector_type(4))) float f32x4;    // MFMA C/D

__device__ __forceinline__ float leakyf(float v) { return v >= 0.f ? v : SLOPE * v; }

// fp32 -> bf16 round-to-nearest-even
__device__ __forceinline__ unsigned short f2bf(float f) {
    unsigned int u = __builtin_bit_cast(unsigned int, f);
    u += 0x7FFFu + ((u >> 16) & 1u);
    return (unsigned short)(u >> 16);
}

// prep: w2 -> w2T[c][j] bf16 (both layers), w1 -> w1T[j][k] bf16 (both layers)
__global__ void prep_kernel(const float* __restrict__ w2_0, const float* __restrict__ w2_1,
                            const float* __restrict__ w1_0, const float* __restrict__ w1_1,
                            unsigned short* __restrict__ w2T0, unsigned short* __restrict__ w2T1,
                            unsigned short* __restrict__ w1T0, unsigned short* __restrict__ w1T1)
{
    int idx = blockIdx.x * 256 + threadIdx.x;
    if (idx < HH * HH) {
        int c = idx >> 8, j = idx & 255;
        w2T0[idx] = f2bf(w2_0[j * HH + c]);
        w2T1[idx] = f2bf(w2_1[j * HH + c]);
    }
    if (idx < HH * EAD) {
        int j = idx >> 3, k = idx & 7;
        w1T0[idx] = f2bf(w1_0[k * HH + j]);
        w1T1[idx] = f2bf(w1_1[k * HH + j]);
    }
}

// Fused NNConv message pass, MFMA version.
// h = leaky(ea@w1+b1) via 16x16x32 MFMA (K=8 padded); W = h@w2 via MFMA;
// msg = x[src]@W reduced in LDS; atomic scatter-mean to agg.
template<int COUNT>
__global__ __launch_bounds__(256, 2)
void edge_kernel(const float* __restrict__ x,      // [NN,16]
                 const int*   __restrict__ esrc,   // [NE]
                 const int*   __restrict__ edst,   // [NE]
                 const float* __restrict__ ea,     // [NE,8]
                 const unsigned short* __restrict__ w1T, // [256 j][8 k] bf16
                 const float* __restrict__ b1,     // [256]
                 const unsigned short* __restrict__ w2T, // [256 c][256 j] bf16
                 const float* __restrict__ b2,     // [256]
                 float* __restrict__ agg,          // [NN,16]
                 float* __restrict__ cnt)          // [NN]
{
    __shared__ __align__(16) unsigned short h_us[EPB * HH]; // 32 KB, XOR-swizzled rows
    __shared__ float xs[EPB][DIN];                          // 4 KB
    __shared__ float msg_s[EPB][DOUT];                      // 4 KB

    const int tid = threadIdx.x;
    const int e0  = blockIdx.x * EPB;
    const int w   = tid >> 6;   // wave 0..3 -> col slab 64w..64w+63
    const int ln  = tid & 63;
    const int lo  = ln & 15;
    const int g4  = ln >> 4;    // 0..3

    // zero msg accumulator (1024 floats)
    #pragma unroll
    for (int z = 0; z < 4; ++z) ((float*)msg_s)[z * 256 + tid] = 0.f;

    // gather x[src]: 64 edges x 16 f32 (4 lanes per edge, float4 each)
    {
        int t = tid >> 2, p = tid & 3;
        int s = esrc[e0 + t];
        *(float4*)&xs[t][p * 4] = *(const float4*)(x + (size_t)s * DIN + p * 4);
    }

    // ---- phase 1: h = leaky(ea @ w1 + b1) via MFMA (K padded 8->32) ----
    bf16x8 zero8;
    #pragma unroll
    for (int k = 0; k < 8; ++k) zero8[k] = 0;

    bf16x8 aE[4], bW[4];
    #pragma unroll
    for (int mt = 0; mt < 4; ++mt) aE[mt] = zero8;
    #pragma unroll
    for (int nt = 0; nt < 4; ++nt) bW[nt] = zero8;

    if (ln < 16) {  // lanes 0-15 carry k=0..7 (real); lanes 16-63 carry zeros
        #pragma unroll
        for (int mt = 0; mt < 4; ++mt) {
            const float* p = ea + (size_t)(e0 + 16 * mt + lo) * EAD;
            bf16x8 v;
            #pragma unroll
            for (int k = 0; k < 8; ++k) v[k] = (short)f2bf(p[k]);
            aE[mt] = v;
        }
        #pragma unroll
        for (int nt = 0; nt < 4; ++nt) {
            int j = 64 * w + 16 * nt + lo;
            bW[nt] = *(const bf16x8*)(w1T + j * EAD);
        }
    }

    f32x4 hacc[4][4];
    #pragma unroll
    for (int nt = 0; nt < 4; ++nt) {
        float bv = b1[64 * w + 16 * nt + lo];
        f32x4 bi; bi[0] = bv; bi[1] = bv; bi[2] = bv; bi[3] = bv;
        #pragma unroll
        for (int mt = 0; mt < 4; ++mt) hacc[mt][nt] = bi;
    }
    #pragma unroll
    for (int mt = 0; mt < 4; ++mt)
        #pragma unroll
        for (int nt = 0; nt < 4; ++nt)
            hacc[mt][nt] = __builtin_amdgcn_mfma_f32_16x16x32_bf16(aE[mt], bW[nt], hacc[mt][nt], 0, 0, 0);

    // leaky + bf16 pack + swizzled LDS store. D layout: col=lane&15, row=(lane>>4)*4+r
    #pragma unroll
    for (int mt = 0; mt < 4; ++mt)
        #pragma unroll
        for (int nt = 0; nt < 4; ++nt)
            #pragma unroll
            for (int r = 0; r < 4; ++r) {
                int t = 16 * mt + 4 * g4 + r;
                int j = 64 * w + 16 * nt + lo;
                h_us[(t * HH + j) ^ ((t & 7) << 3)] = f2bf(leakyf(hacc[mt][nt][r]));
            }
    __syncthreads();

    // ---- phase 2: W = h @ w2  (M=64 edges, N=256 cols, K=256) ----
    f32x4 acc[4][4];
    {
        f32x4 z4; z4[0] = 0.f; z4[1] = 0.f; z4[2] = 0.f; z4[3] = 0.f;
        #pragma unroll
        for (int mt = 0; mt < 4; ++mt)
            #pragma unroll
            for (int nt = 0; nt < 4; ++nt) acc[mt][nt] = z4;
    }
    // B-frag: lane holds w2T[c=64w+16nt+lo][j=32ks+8g4 .. +8]; register double-buffer
    const unsigned short* bbase = w2T + (size_t)(64 * w + lo) * HH + 8 * g4;
    bf16x8 bcur[4], bnxt[4];
    #pragma unroll
    for (int nt = 0; nt < 4; ++nt) bcur[nt] = *(const bf16x8*)(bbase + nt * 16 * HH);
    #pragma unroll
    for (int nt = 0; nt < 4; ++nt) bnxt[nt] = bcur[nt];

    #pragma unroll
    for (int ks = 0; ks < 8; ++ks) {
        if (ks < 7) {
            #pragma unroll
            for (int nt = 0; nt < 4; ++nt)
                bnxt[nt] = *(const bf16x8*)(bbase + nt * 16 * HH + 32 * (ks + 1));
        }
        bf16x8 af[4];   // A-frag: lane holds h[t=16mt+lo][j=32ks+8g4 .. +8]
        #pragma unroll
        for (int mt = 0; mt < 4; ++mt) {
            int t = 16 * mt + lo;
            af[mt] = *(const bf16x8*)(h_us + ((t * HH + 32 * ks + 8 * g4) ^ ((t & 7) << 3)));
        }
        #pragma unroll
        for (int mt = 0; mt < 4; ++mt)
            #pragma unroll
            for (int nt = 0; nt < 4; ++nt)
                acc[mt][nt] = __builtin_amdgcn_mfma_f32_16x16x32_bf16(af[mt], bcur[nt], acc[mt][nt], 0, 0, 0);
        #pragma unroll
        for (int nt = 0; nt < 4; ++nt) bcur[nt] = bnxt[nt];
    }

    // ---- epilogue: msg[t][o] += sum_i xs[t][i] * W[t][16i+o] ----
    // lane's col c = 64w+16nt+lo  ->  i = 4w+nt, o = lo
    #pragma unroll
    for (int mt = 0; mt < 4; ++mt)
        #pragma unroll
        for (int r = 0; r < 4; ++r) {
            int t = 16 * mt + 4 * g4 + r;
            float ps = 0.f;
            #pragma unroll
            for (int nt = 0; nt < 4; ++nt)
                ps += xs[t][4 * w + nt] * acc[mt][nt][r];
            atomicAdd(&msg_s[t][lo], ps);
        }
    __syncthreads();

    // ---- scatter: 4 lanes/edge, 4 outputs each; + b2 term; global atomics ----
    {
        int t = tid >> 2, og = tid & 3;
        int d = edst[e0 + t];
        #pragma unroll
        for (int oo = 0; oo < 4; ++oo) {
            int o = og * 4 + oo;
            float m = msg_s[t][o];
            #pragma unroll
            for (int i = 0; i < DIN; ++i)
                m += xs[t][i] * b2[i * DOUT + o];
            atomicAdd(&agg[(size_t)d * DOUT + o], m);
        }
        if (COUNT && og == 0) atomicAdd(&cnt[d], 1.0f);
    }
}

// out[n][o] = agg[n][o]/max(cnt,1) + x[n]@root[:,o] + bias[o]  (opt leaky)
__global__ void finalize_kernel(const float* __restrict__ agg,
                                const float* __restrict__ cnt,
                                const float* __restrict__ xin,
                                const float* __restrict__ root, // [16,16]
                                const float* __restrict__ bias, // [16]
                                float* __restrict__ out,
                                int do_leaky)
{
    int idx = blockIdx.x * blockDim.x + threadIdx.x;
    if (idx >= NN * DOUT) return;
    int n = idx >> 4, o = idx & 15;
    float c = cnt[n];
    c = c > 1.f ? c : 1.f;
    float v = agg[idx] / c;
    #pragma unroll
    for (int i = 0; i < DIN; ++i)
        v += xin[n * DIN + i] * root[i * DOUT + o];
    v += bias[o];
    out[idx] = do_leaky ? leakyf(v) : v;
}

extern "C" void kernel_launch(void* const* d_in, const int* in_sizes, int n_in,
                              void* d_out, int out_size, void* d_ws, size_t ws_size,
                              hipStream_t stream)
{
    const float* x      = (const float*)d_in[0];
    const int*   ei     = (const int*)  d_in[1];
    const float* ea     = (const float*)d_in[2];
    const float* w1_0   = (const float*)d_in[3];
    const float* b1_0   = (const float*)d_in[4];
    const float* w2_0   = (const float*)d_in[5];
    const float* b2_0   = (const float*)d_in[6];
    const float* root_0 = (const float*)d_in[7];
    const float* bias_0 = (const float*)d_in[8];
    const float* w1_1   = (const float*)d_in[9];
    const float* b1_1   = (const float*)d_in[10];
    const float* w2_1   = (const float*)d_in[11];
    const float* b2_1   = (const float*)d_in[12];
    const float* root_1 = (const float*)d_in[13];
    const float* bias_1 = (const float*)d_in[14];

    const int* esrc = ei;
    const int* edst = ei + NE;

    // ws: w2T0 | w2T1 | w1T0 | w1T1 (bf16) | agg | cnt | x1 (f32)
    unsigned short* w2T0 = (unsigned short*)d_ws;
    unsigned short* w2T1 = w2T0 + HH * HH;
    unsigned short* w1T0 = w2T1 + HH * HH;
    unsigned short* w1T1 = w1T0 + HH * EAD;
    float* agg = (float*)(w1T1 + HH * EAD);
    float* cnt = agg + (size_t)NN * DOUT;
    float* x1  = cnt + NN;
    const size_t ws_need = (size_t)(2 * HH * HH + 2 * HH * EAD) * 2
                         + (size_t)(2 * NN * DOUT + NN) * 4;
    if (ws_size < ws_need) return;  // fail clean (absmax), not a GPU fault

    hipMemsetAsync(agg, 0, ((size_t)NN * DOUT + NN) * sizeof(float), stream);
    prep_kernel<<<HH * HH / 256, 256, 0, stream>>>(w2_0, w2_1, w1_0, w1_1,
                                                   w2T0, w2T1, w1T0, w1T1);

    edge_kernel<1><<<NE / EPB, 256, 0, stream>>>(x, esrc, edst, ea,
                                                 w1T0, b1_0, w2T0, b2_0, agg, cnt);
    finalize_kernel<<<(NN * DOUT + 255) / 256, 256, 0, stream>>>(agg, cnt, x,
                                                 root_0, bias_0, x1, 1);
    hipMemsetAsync(agg, 0, (size_t)NN * DOUT * sizeof(float), stream);

    edge_kernel<0><<<NE / EPB, 256, 0, stream>>>(x1, esrc, edst, ea,
                                                 w1T1, b1_1, w2T1, b2_1, agg, cnt);
    finalize_kernel<<<(NN * DOUT + 255) / 256, 256, 0, stream>>>(agg, cnt, x1,
                                                 root_1, bias_1, (float*)d_out, 0);
}